// Round 13
// baseline (130.756 us; speedup 1.0000x reference)
//
#include <hip/hip_runtime.h>
#include <hip/hip_fp16.h>

#define HW 128
#define PLANE (HW * HW)
#define WSTR 72   // shorts per window record (20x20 halo), 144 B row
#define OSTR 22   // floats per offsL pixel row

typedef __attribute__((ext_vector_type(8))) _Float16 f16x8;
typedef __attribute__((ext_vector_type(4))) float f32x4;

__device__ __forceinline__ unsigned short f2h(float f) {
  return __half_as_ushort(__float2half(f));
}

// XCD-aware bijective swizzle (nwg % 8 == 0): XCD k gets a contiguous chunk.
__device__ __forceinline__ void tile_from_bid_512(int bid, int& b, int& by, int& bx) {
  int wg = (bid & 7) * 64 + (bid >> 3);
  b = wg >> 6;
  int t = wg & 63;
  by = (t >> 3) << 4;
  bx = (t & 7) << 4;
}

// ---------------- fused weight packing (all three) ----------------
__global__ __launch_bounds__(256) void pack_all_kernel(
    const float* __restrict__ w1, const float* __restrict__ w2,
    const float* __restrict__ wd, unsigned short* __restrict__ w1p,
    unsigned short* __restrict__ w2p, unsigned short* __restrict__ wdp) {
  int idx = blockIdx.x * 256 + threadIdx.x;
  if (idx < 73728) {
    int k = idx >> 6, n = idx & 63;
    int tap = k >> 7, ic = k & 127;
    w1p[((k >> 3) * 64 + n) * 8 + (k & 7)] = f2h(w1[(n * 128 + ic) * 9 + tap]);
  } else if (idx < 73728 + 18432) {
    int i = idx - 73728;
    int k = i >> 5, n = i & 31;
    int tap = k >> 6, ic = k & 63;
    float v = (n < 18) ? w2[(n * 64 + ic) * 9 + tap] : 0.f;
    w2p[((k >> 3) * 32 + n) * 8 + (k & 7)] = f2h(v);
  } else if (idx < 73728 + 18432 + 36864) {
    int i = idx - 73728 - 18432;
    int k = i >> 6, n = i & 63;
    int tap = k >> 6, ic = k & 63;
    wdp[((k >> 3) * 64 + n) * 8 + (k & 7)] = f2h(wd[(n * 64 + ic) * 9 + tap]);
  }
}

// ---------------- ref,tgt NCHW fp32 -> NHWC fp16 ----------------
__global__ __launch_bounds__(256) void to_nhwc_kernel(
    const float* __restrict__ ref, const float* __restrict__ tgt,
    unsigned short* __restrict__ xref, unsigned short* __restrict__ xtgt) {
  __shared__ unsigned short lds[32][136];
  const int b = blockIdx.z, y = blockIdx.y, x0 = blockIdx.x * 32;
  for (int idx = threadIdx.x; idx < 4096; idx += 256) {
    int ic = idx >> 5, px = idx & 31;
    const float* src = (ic < 64) ? ref : tgt;
    lds[px][ic] = f2h(src[(b * 64 + (ic & 63)) * PLANE + y * HW + x0 + px]);
  }
  __syncthreads();
  for (int idx = threadIdx.x; idx < 512; idx += 256) {
    int px = idx >> 4, g = idx & 15;
    uint4 v = *(const uint4*)&lds[px][g * 8];
    size_t base = ((size_t)(b * HW + y) * HW + x0 + px) * 64;
    if (g < 8)
      *(uint4*)(xref + base + g * 8) = v;
    else
      *(uint4*)(xtgt + base + (g - 8) * 8) = v;
  }
}

__device__ __forceinline__ uint4 blend4(uint4 a, uint4 b, uint4 c, uint4 d,
                                        __half2 h00, __half2 h01, __half2 h10, __half2 h11) {
  union U { uint4 u; __half2 h[4]; };
  U A, B, C, D, R;
  A.u = a; B.u = b; C.u = c; D.u = d;
#pragma unroll
  for (int i = 0; i < 4; ++i)
    R.h[i] = __hfma2(D.h[i], h11, __hfma2(C.h[i], h10, __hfma2(B.h[i], h01, __hmul2(A.h[i], h00))));
  return R.u;
}

// ---------------- megakernel v5: v2 structure + STATIC-indexed weight dbuf ----------------
// Exactly round-10 v2 (stride-72 window, 7 barriers, 2 blocks/CU, no XOR) plus
// weight double-buffering with compile-time-constant array indices (wb[it&1]) —
// rule-#20-safe, unlike round-11's pointer selection which spilled to scratch.
__global__ __launch_bounds__(512, 4) void mega_kernel(
    const unsigned short* __restrict__ xref, const unsigned short* __restrict__ xtgt,
    const unsigned short* __restrict__ w1p, const float* __restrict__ b1,
    const unsigned short* __restrict__ w2p, const float* __restrict__ b2,
    const unsigned short* __restrict__ wdp, float* __restrict__ out) {
  __shared__ __align__(16) unsigned short bufW[400 * WSTR];  // 57600 B
  __shared__ __align__(8) float offsL[256 * OSTR];           // 22528 B; total 80128 B

  int b, by, bx;
  tile_from_bid_512(blockIdx.x, b, by, bx);
  const int tid = threadIdx.x, lane = tid & 63, w = tid >> 6;
  const int l15 = lane & 15, lg = lane >> 4;

  const unsigned short* rb = xref + (size_t)b * PLANE * 64;
  const unsigned short* tb = xtgt + (size_t)b * PLANE * 64;

  auto STAGE = [&](const unsigned short* src) {
    for (int i = tid; i < 3200; i += 512) {
      int rec = i >> 3, g = i & 7;
      int wy = rec / 20, wx = rec - wy * 20;
      int gy = by - 2 + wy, gx = bx - 2 + wx;
      uint4 v = make_uint4(0u, 0u, 0u, 0u);
      if ((unsigned)gy < 128u && (unsigned)gx < 128u)
        v = *(const uint4*)(src + ((size_t)gy * HW + gx) * 64 + g * 8);
      *(uint4*)(bufW + rec * WSTR + g * 8) = v;
    }
  };

  int pyv[3], pxv[3];
#pragma unroll
  for (int n = 0; n < 3; ++n) {
    int p = (w * 3 + n) * 16 + l15;
    p = min(p, 323);
    pyv[n] = p / 18;
    pxv[n] = p - pyv[n] * 18;
  }

  f32x4 acc1[4][3];
#pragma unroll
  for (int mf = 0; mf < 4; ++mf)
#pragma unroll
    for (int n = 0; n < 3; ++n) acc1[mf][n] = (f32x4){0.f, 0.f, 0.f, 0.f};

  // conv1 K-half; weight dbuf with STATIC indices (it&1 is const after unroll)
  auto CONV1_HALF = [&](int c) {
    f16x8 wb[2][4];
#pragma unroll
    for (int mf = 0; mf < 4; ++mf)
      wb[0][mf] = *(const f16x8*)(w1p + ((c * 8 + lg) * 64 + mf * 16 + l15) * 8);
#pragma unroll
    for (int it = 0; it < 18; ++it) {
      if (it < 17) {
        const int tap2 = (it + 1) >> 1, ks2 = (it + 1) & 1;
        const int kb = tap2 * 16 + c * 8 + ks2 * 4 + lg;
#pragma unroll
        for (int mf = 0; mf < 4; ++mf)
          wb[(it + 1) & 1][mf] = *(const f16x8*)(w1p + (kb * 64 + mf * 16 + l15) * 8);
      }
      const int tap = it >> 1, ks = it & 1;
      const int ty = tap / 3, tx = tap - ty * 3;
      f16x8 bp[3];
#pragma unroll
      for (int n = 0; n < 3; ++n) {
        int rec = (pyv[n] + ty) * 20 + pxv[n] + tx;
        bp[n] = *(const f16x8*)(bufW + rec * WSTR + ks * 32 + lg * 8);
      }
#pragma unroll
      for (int mf = 0; mf < 4; ++mf)
#pragma unroll
        for (int n = 0; n < 3; ++n)
          acc1[mf][n] = __builtin_amdgcn_mfma_f32_16x16x32_f16(wb[it & 1][mf], bp[n], acc1[mf][n], 0, 0, 0);
    }
  };

  STAGE(tb);            // s1: tgt window
  __syncthreads();
  CONV1_HALF(1);        // s2: tgt half of K
  __syncthreads();
  STAGE(rb);            // s3: ref window (overwrite)
  __syncthreads();
  CONV1_HALF(0);        // s4: ref half of K
  __syncthreads();

  // s5: hmid -> bufW overlay (18x18, stride WSTR), MASKED to 0 outside image
  unsigned short* hmidL = bufW;
#pragma unroll
  for (int mf = 0; mf < 4; ++mf) {
    const float4 bv = ((const float4*)b1)[mf * 4 + lg];
#pragma unroll
    for (int n = 0; n < 3; ++n) {
      const int p = (w * 3 + n) * 16 + l15;
      const bool valid = ((unsigned)(by - 1 + pyv[n]) < 128u) &&
                         ((unsigned)(bx - 1 + pxv[n]) < 128u);
      const float m = valid ? 1.f : 0.f;
      float v0 = acc1[mf][n][0] + bv.x;
      float v1 = acc1[mf][n][1] + bv.y;
      float v2 = acc1[mf][n][2] + bv.z;
      float v3 = acc1[mf][n][3] + bv.w;
      v0 = ((v0 >= 0.f) ? v0 : 0.1f * v0) * m;
      v1 = ((v1 >= 0.f) ? v1 : 0.1f * v1) * m;
      v2 = ((v2 >= 0.f) ? v2 : 0.1f * v2) * m;
      v3 = ((v3 >= 0.f) ? v3 : 0.1f * v3) * m;
      ushort4 s;
      s.x = f2h(v0); s.y = f2h(v1); s.z = f2h(v2); s.w = f2h(v3);
      *(ushort4*)(hmidL + p * WSTR + mf * 16 + lg * 4) = s;
    }
  }
  __syncthreads();

  // s6: conv2 with static-indexed weight dbuf
  f32x4 acc2[2][2];
#pragma unroll
  for (int q = 0; q < 2; ++q)
#pragma unroll
    for (int nf = 0; nf < 2; ++nf) acc2[q][nf] = (f32x4){0.f, 0.f, 0.f, 0.f};

  {
    f16x8 wb2[2][2];
#pragma unroll
    for (int nf = 0; nf < 2; ++nf)
      wb2[0][nf] = *(const f16x8*)(w2p + (lg * 32 + nf * 16 + l15) * 8);
#pragma unroll
    for (int it = 0; it < 18; ++it) {
      if (it < 17) {
        const int kb = (it + 1) * 4 + lg;
#pragma unroll
        for (int nf = 0; nf < 2; ++nf)
          wb2[(it + 1) & 1][nf] = *(const f16x8*)(w2p + (kb * 32 + nf * 16 + l15) * 8);
      }
      const int tap = it >> 1, ks = it & 1;
      const int ty = tap / 3, tx = tap - ty * 3;
      f16x8 ap[2];
#pragma unroll
      for (int q = 0; q < 2; ++q) {
        int p = (w * 2 + q + ty) * 18 + l15 + tx;
        ap[q] = *(const f16x8*)(hmidL + p * WSTR + ks * 32 + lg * 8);
      }
#pragma unroll
      for (int q = 0; q < 2; ++q)
#pragma unroll
        for (int nf = 0; nf < 2; ++nf)
          acc2[q][nf] = __builtin_amdgcn_mfma_f32_16x16x32_f16(ap[q], wb2[it & 1][nf], acc2[q][nf], 0, 0, 0);
    }
  }
#pragma unroll
  for (int nf = 0; nf < 2; ++nf) {
    const int oc = nf * 16 + l15;
    if (oc < 18) {
      const float bias = b2[oc];
#pragma unroll
      for (int q = 0; q < 2; ++q)
#pragma unroll
        for (int reg = 0; reg < 4; ++reg) {
          int px = (w * 2 + q) * 16 + lg * 4 + reg;
          offsL[px * OSTR + oc] = acc2[q][nf][reg] + bias;
        }
    }
  }
  __syncthreads();

  STAGE(tb);            // s7: re-stage tgt window
  __syncthreads();

  // s8: deform; wd dbuf indexed by ks (parity(jt)=ks, static even with runtime kk)
  f32x4 acc[2][4];
#pragma unroll
  for (int q = 0; q < 2; ++q)
#pragma unroll
    for (int nf = 0; nf < 4; ++nf) acc[q][nf] = (f32x4){0.f, 0.f, 0.f, 0.f};

  const int x = bx + l15;

  f16x8 wbd[2][4];
#pragma unroll
  for (int nf = 0; nf < 4; ++nf)
    wbd[0][nf] = *(const f16x8*)(wdp + (lg * 64 + nf * 16 + l15) * 8);

  for (int kk = 0; kk < 9; ++kk) {
    const int kdy = kk / 3 - 1, kdx = kk - (kk / 3) * 3 - 1;
    f16x8 af[2][2];
#pragma unroll
    for (int q = 0; q < 2; ++q) {
      const int y = by + w * 2 + q;
      const int px_lin = (w * 2 + q) * 16 + l15;
      const float2 o2 = *(const float2*)(&offsL[px_lin * OSTR + kk * 2]);
      float ys = (float)(y + kdy) + o2.x;
      float xs = (float)(x + kdx) + o2.y;
      float y0f = floorf(ys), x0f = floorf(xs);
      float wy = ys - y0f, wx = xs - x0f;
      int y0 = (int)y0f, x0i = (int)x0f;
      int y1 = y0 + 1, x1 = x0i + 1;
      float vy0 = (y0 >= 0 && y0 < HW) ? 1.f : 0.f;
      float vy1 = (y1 >= 0 && y1 < HW) ? 1.f : 0.f;
      float vx0 = (x0i >= 0 && x0i < HW) ? 1.f : 0.f;
      float vx1 = (x1 >= 0 && x1 < HW) ? 1.f : 0.f;
      int y0c = min(max(y0, 0), HW - 1), y1c = min(max(y1, 0), HW - 1);
      int x0c = min(max(x0i, 0), HW - 1), x1c = min(max(x1, 0), HW - 1);
      __half2 h00 = __float2half2_rn((1.f - wy) * (1.f - wx) * vy0 * vx0);
      __half2 h01 = __float2half2_rn((1.f - wy) * wx * vy0 * vx1);
      __half2 h10 = __float2half2_rn(wy * (1.f - wx) * vy1 * vx0);
      __half2 h11 = __float2half2_rn(wy * wx * vy1 * vx1);

      const int wy0 = y0c - by + 2, wy1 = y1c - by + 2;
      const int wx0 = x0c - bx + 2, wx1 = x1c - bx + 2;
      const bool inw = ((unsigned)wy0 < 20u) && ((unsigned)wy1 < 20u) &&
                       ((unsigned)wx0 < 20u) && ((unsigned)wx1 < 20u);
      const int r00 = wy0 * 20 + wx0, r01 = wy0 * 20 + wx1;
      const int r10 = wy1 * 20 + wx0, r11 = wy1 * 20 + wx1;
      const unsigned short* p00 = tb + (y0c * HW + x0c) * 64 + lg * 8;
      const unsigned short* p01 = tb + (y0c * HW + x1c) * 64 + lg * 8;
      const unsigned short* p10 = tb + (y1c * HW + x0c) * 64 + lg * 8;
      const unsigned short* p11 = tb + (y1c * HW + x1c) * 64 + lg * 8;
#pragma unroll
      for (int ks = 0; ks < 2; ++ks) {
        uint4 c0, c1, c2, c3;
        const int ko = ks * 32 + lg * 8;
        if (inw) {
          c0 = *(const uint4*)(bufW + r00 * WSTR + ko);
          c1 = *(const uint4*)(bufW + r01 * WSTR + ko);
          c2 = *(const uint4*)(bufW + r10 * WSTR + ko);
          c3 = *(const uint4*)(bufW + r11 * WSTR + ko);
        } else {
          c0 = *(const uint4*)(p00 + ks * 32);
          c1 = *(const uint4*)(p01 + ks * 32);
          c2 = *(const uint4*)(p10 + ks * 32);
          c3 = *(const uint4*)(p11 + ks * 32);
        }
        uint4 r = blend4(c0, c1, c2, c3, h00, h01, h10, h11);
        af[q][ks] = *(const f16x8*)&r;
      }
    }

#pragma unroll
    for (int ks = 0; ks < 2; ++ks) {
      const int jt = kk * 2 + ks;
      if (jt < 17) {
        const int kb = (jt + 1) * 4 + lg;
#pragma unroll
        for (int nf = 0; nf < 4; ++nf)
          wbd[ks ^ 1][nf] = *(const f16x8*)(wdp + (kb * 64 + nf * 16 + l15) * 8);
      }
#pragma unroll
      for (int q = 0; q < 2; ++q)
#pragma unroll
        for (int nf = 0; nf < 4; ++nf)
          acc[q][nf] = __builtin_amdgcn_mfma_f32_16x16x32_f16(af[q][ks], wbd[ks][nf], acc[q][nf], 0, 0, 0);
    }
  }

  const int px0 = bx + lg * 4;
#pragma unroll
  for (int q = 0; q < 2; ++q) {
    const int py = by + w * 2 + q;
#pragma unroll
    for (int nf = 0; nf < 4; ++nf) {
      const int oc = nf * 16 + l15;
      float4 o;
      o.x = acc[q][nf][0];
      o.y = acc[q][nf][1];
      o.z = acc[q][nf][2];
      o.w = acc[q][nf][3];
      *(float4*)(out + (size_t)(b * 64 + oc) * PLANE + py * HW + px0) = o;
    }
  }
}

extern "C" void kernel_launch(void* const* d_in, const int* in_sizes, int n_in,
                              void* d_out, int out_size, void* d_ws, size_t ws_size,
                              hipStream_t stream) {
  const float* ref = (const float*)d_in[0];
  const float* tgt = (const float*)d_in[1];
  const float* w1  = (const float*)d_in[2];
  const float* b1  = (const float*)d_in[3];
  const float* w2  = (const float*)d_in[4];
  const float* b2  = (const float*)d_in[5];
  const float* wd  = (const float*)d_in[6];
  float* out = (float*)d_out;

  char* ws = (char*)d_ws;
  unsigned short* xref = (unsigned short*)ws;                   // 16777216 B
  unsigned short* xtgt = (unsigned short*)(ws + 16777216);      // 16777216 B
  unsigned short* w1p  = (unsigned short*)(ws + 33554432);      // 147456 B
  unsigned short* w2p  = (unsigned short*)(ws + 33701888);      // 36864 B
  unsigned short* wdp  = (unsigned short*)(ws + 33738752);      // 73728 B; end = 33812480

  pack_all_kernel<<<504, 256, 0, stream>>>(w1, w2, wd, w1p, w2p, wdp);

  to_nhwc_kernel<<<dim3(4, 128, 8), 256, 0, stream>>>(ref, tgt, xref, xtgt);

  mega_kernel<<<512, 512, 0, stream>>>(xref, xtgt, w1p, b1, w2p, b2, wdp, out);
}

// Round 14
// 127.191 us; speedup vs baseline: 1.0280x; 1.0280x over previous
//
#include <hip/hip_runtime.h>
#include <hip/hip_fp16.h>

#define HW 128
#define PLANE (HW * HW)
#define WSTR 72   // shorts per window record (20x20 halo), 144 B row
#define OSTR 22   // floats per offsL pixel row

typedef __attribute__((ext_vector_type(8))) _Float16 f16x8;
typedef __attribute__((ext_vector_type(4))) float f32x4;

__device__ __forceinline__ unsigned short f2h(float f) {
  return __half_as_ushort(__float2half(f));
}

// XCD-aware bijective swizzle (nwg % 8 == 0): XCD k gets a contiguous chunk.
__device__ __forceinline__ void tile_from_bid_512(int bid, int& b, int& by, int& bx) {
  int wg = (bid & 7) * 64 + (bid >> 3);
  b = wg >> 6;
  int t = wg & 63;
  by = (t >> 3) << 4;
  bx = (t & 7) << 4;
}

// ---------------- fused weight packing (all three) ----------------
__global__ __launch_bounds__(256) void pack_all_kernel(
    const float* __restrict__ w1, const float* __restrict__ w2,
    const float* __restrict__ wd, unsigned short* __restrict__ w1p,
    unsigned short* __restrict__ w2p, unsigned short* __restrict__ wdp) {
  int idx = blockIdx.x * 256 + threadIdx.x;
  if (idx < 73728) {
    int k = idx >> 6, n = idx & 63;
    int tap = k >> 7, ic = k & 127;
    w1p[((k >> 3) * 64 + n) * 8 + (k & 7)] = f2h(w1[(n * 128 + ic) * 9 + tap]);
  } else if (idx < 73728 + 18432) {
    int i = idx - 73728;
    int k = i >> 5, n = i & 31;
    int tap = k >> 6, ic = k & 63;
    float v = (n < 18) ? w2[(n * 64 + ic) * 9 + tap] : 0.f;
    w2p[((k >> 3) * 32 + n) * 8 + (k & 7)] = f2h(v);
  } else if (idx < 73728 + 18432 + 36864) {
    int i = idx - 73728 - 18432;
    int k = i >> 6, n = i & 63;
    int tap = k >> 6, ic = k & 63;
    wdp[((k >> 3) * 64 + n) * 8 + (k & 7)] = f2h(wd[(n * 64 + ic) * 9 + tap]);
  }
}

// ---------------- ref,tgt NCHW fp32 -> NHWC fp16 ----------------
__global__ __launch_bounds__(256) void to_nhwc_kernel(
    const float* __restrict__ ref, const float* __restrict__ tgt,
    unsigned short* __restrict__ xref, unsigned short* __restrict__ xtgt) {
  __shared__ unsigned short lds[32][136];
  const int b = blockIdx.z, y = blockIdx.y, x0 = blockIdx.x * 32;
  for (int idx = threadIdx.x; idx < 4096; idx += 256) {
    int ic = idx >> 5, px = idx & 31;
    const float* src = (ic < 64) ? ref : tgt;
    lds[px][ic] = f2h(src[(b * 64 + (ic & 63)) * PLANE + y * HW + x0 + px]);
  }
  __syncthreads();
  for (int idx = threadIdx.x; idx < 512; idx += 256) {
    int px = idx >> 4, g = idx & 15;
    uint4 v = *(const uint4*)&lds[px][g * 8];
    size_t base = ((size_t)(b * HW + y) * HW + x0 + px) * 64;
    if (g < 8)
      *(uint4*)(xref + base + g * 8) = v;
    else
      *(uint4*)(xtgt + base + (g - 8) * 8) = v;
  }
}

__device__ __forceinline__ uint4 blend4(uint4 a, uint4 b, uint4 c, uint4 d,
                                        __half2 h00, __half2 h01, __half2 h10, __half2 h11) {
  union U { uint4 u; __half2 h[4]; };
  U A, B, C, D, R;
  A.u = a; B.u = b; C.u = c; D.u = d;
#pragma unroll
  for (int i = 0; i < 4; ++i)
    R.h[i] = __hfma2(D.h[i], h11, __hfma2(C.h[i], h10, __hfma2(B.h[i], h01, __hmul2(A.h[i], h00))));
  return R.u;
}

// ---------------- megakernel v6: v5 static-indexed dbuf + relaxed VGPR bound ----------------
// Identical to round-13 v5 except __launch_bounds__(512, 2): allows ~128 VGPRs so
// the weight double-buffers live in registers instead of scratch (rounds 11/13
// spilled under the 64-reg wall of (512,4)). Occupancy stays LDS-limited at
// 2 blocks/CU (80128 B), so nothing is traded away.
__global__ __launch_bounds__(512, 2) void mega_kernel(
    const unsigned short* __restrict__ xref, const unsigned short* __restrict__ xtgt,
    const unsigned short* __restrict__ w1p, const float* __restrict__ b1,
    const unsigned short* __restrict__ w2p, const float* __restrict__ b2,
    const unsigned short* __restrict__ wdp, float* __restrict__ out) {
  __shared__ __align__(16) unsigned short bufW[400 * WSTR];  // 57600 B
  __shared__ __align__(8) float offsL[256 * OSTR];           // 22528 B; total 80128 B

  int b, by, bx;
  tile_from_bid_512(blockIdx.x, b, by, bx);
  const int tid = threadIdx.x, lane = tid & 63, w = tid >> 6;
  const int l15 = lane & 15, lg = lane >> 4;

  const unsigned short* rb = xref + (size_t)b * PLANE * 64;
  const unsigned short* tb = xtgt + (size_t)b * PLANE * 64;

  auto STAGE = [&](const unsigned short* src) {
    for (int i = tid; i < 3200; i += 512) {
      int rec = i >> 3, g = i & 7;
      int wy = rec / 20, wx = rec - wy * 20;
      int gy = by - 2 + wy, gx = bx - 2 + wx;
      uint4 v = make_uint4(0u, 0u, 0u, 0u);
      if ((unsigned)gy < 128u && (unsigned)gx < 128u)
        v = *(const uint4*)(src + ((size_t)gy * HW + gx) * 64 + g * 8);
      *(uint4*)(bufW + rec * WSTR + g * 8) = v;
    }
  };

  int pyv[3], pxv[3];
#pragma unroll
  for (int n = 0; n < 3; ++n) {
    int p = (w * 3 + n) * 16 + l15;
    p = min(p, 323);
    pyv[n] = p / 18;
    pxv[n] = p - pyv[n] * 18;
  }

  f32x4 acc1[4][3];
#pragma unroll
  for (int mf = 0; mf < 4; ++mf)
#pragma unroll
    for (int n = 0; n < 3; ++n) acc1[mf][n] = (f32x4){0.f, 0.f, 0.f, 0.f};

  // conv1 K-half; weight dbuf with STATIC indices (it&1 is const after unroll)
  auto CONV1_HALF = [&](int c) {
    f16x8 wb[2][4];
#pragma unroll
    for (int mf = 0; mf < 4; ++mf)
      wb[0][mf] = *(const f16x8*)(w1p + ((c * 8 + lg) * 64 + mf * 16 + l15) * 8);
#pragma unroll
    for (int it = 0; it < 18; ++it) {
      if (it < 17) {
        const int tap2 = (it + 1) >> 1, ks2 = (it + 1) & 1;
        const int kb = tap2 * 16 + c * 8 + ks2 * 4 + lg;
#pragma unroll
        for (int mf = 0; mf < 4; ++mf)
          wb[(it + 1) & 1][mf] = *(const f16x8*)(w1p + (kb * 64 + mf * 16 + l15) * 8);
      }
      const int tap = it >> 1, ks = it & 1;
      const int ty = tap / 3, tx = tap - ty * 3;
      f16x8 bp[3];
#pragma unroll
      for (int n = 0; n < 3; ++n) {
        int rec = (pyv[n] + ty) * 20 + pxv[n] + tx;
        bp[n] = *(const f16x8*)(bufW + rec * WSTR + ks * 32 + lg * 8);
      }
#pragma unroll
      for (int mf = 0; mf < 4; ++mf)
#pragma unroll
        for (int n = 0; n < 3; ++n)
          acc1[mf][n] = __builtin_amdgcn_mfma_f32_16x16x32_f16(wb[it & 1][mf], bp[n], acc1[mf][n], 0, 0, 0);
    }
  };

  STAGE(tb);            // s1: tgt window
  __syncthreads();
  CONV1_HALF(1);        // s2: tgt half of K
  __syncthreads();
  STAGE(rb);            // s3: ref window (overwrite)
  __syncthreads();
  CONV1_HALF(0);        // s4: ref half of K
  __syncthreads();

  // s5: hmid -> bufW overlay (18x18, stride WSTR), MASKED to 0 outside image
  unsigned short* hmidL = bufW;
#pragma unroll
  for (int mf = 0; mf < 4; ++mf) {
    const float4 bv = ((const float4*)b1)[mf * 4 + lg];
#pragma unroll
    for (int n = 0; n < 3; ++n) {
      const int p = (w * 3 + n) * 16 + l15;
      const bool valid = ((unsigned)(by - 1 + pyv[n]) < 128u) &&
                         ((unsigned)(bx - 1 + pxv[n]) < 128u);
      const float m = valid ? 1.f : 0.f;
      float v0 = acc1[mf][n][0] + bv.x;
      float v1 = acc1[mf][n][1] + bv.y;
      float v2 = acc1[mf][n][2] + bv.z;
      float v3 = acc1[mf][n][3] + bv.w;
      v0 = ((v0 >= 0.f) ? v0 : 0.1f * v0) * m;
      v1 = ((v1 >= 0.f) ? v1 : 0.1f * v1) * m;
      v2 = ((v2 >= 0.f) ? v2 : 0.1f * v2) * m;
      v3 = ((v3 >= 0.f) ? v3 : 0.1f * v3) * m;
      ushort4 s;
      s.x = f2h(v0); s.y = f2h(v1); s.z = f2h(v2); s.w = f2h(v3);
      *(ushort4*)(hmidL + p * WSTR + mf * 16 + lg * 4) = s;
    }
  }
  __syncthreads();

  // s6: conv2 with static-indexed weight dbuf
  f32x4 acc2[2][2];
#pragma unroll
  for (int q = 0; q < 2; ++q)
#pragma unroll
    for (int nf = 0; nf < 2; ++nf) acc2[q][nf] = (f32x4){0.f, 0.f, 0.f, 0.f};

  {
    f16x8 wb2[2][2];
#pragma unroll
    for (int nf = 0; nf < 2; ++nf)
      wb2[0][nf] = *(const f16x8*)(w2p + (lg * 32 + nf * 16 + l15) * 8);
#pragma unroll
    for (int it = 0; it < 18; ++it) {
      if (it < 17) {
        const int kb = (it + 1) * 4 + lg;
#pragma unroll
        for (int nf = 0; nf < 2; ++nf)
          wb2[(it + 1) & 1][nf] = *(const f16x8*)(w2p + (kb * 32 + nf * 16 + l15) * 8);
      }
      const int tap = it >> 1, ks = it & 1;
      const int ty = tap / 3, tx = tap - ty * 3;
      f16x8 ap[2];
#pragma unroll
      for (int q = 0; q < 2; ++q) {
        int p = (w * 2 + q + ty) * 18 + l15 + tx;
        ap[q] = *(const f16x8*)(hmidL + p * WSTR + ks * 32 + lg * 8);
      }
#pragma unroll
      for (int q = 0; q < 2; ++q)
#pragma unroll
        for (int nf = 0; nf < 2; ++nf)
          acc2[q][nf] = __builtin_amdgcn_mfma_f32_16x16x32_f16(ap[q], wb2[it & 1][nf], acc2[q][nf], 0, 0, 0);
    }
  }
#pragma unroll
  for (int nf = 0; nf < 2; ++nf) {
    const int oc = nf * 16 + l15;
    if (oc < 18) {
      const float bias = b2[oc];
#pragma unroll
      for (int q = 0; q < 2; ++q)
#pragma unroll
        for (int reg = 0; reg < 4; ++reg) {
          int px = (w * 2 + q) * 16 + lg * 4 + reg;
          offsL[px * OSTR + oc] = acc2[q][nf][reg] + bias;
        }
    }
  }
  __syncthreads();

  STAGE(tb);            // s7: re-stage tgt window
  __syncthreads();

  // s8: deform; wd dbuf indexed by ks (parity(jt)=ks, static even with runtime kk)
  f32x4 acc[2][4];
#pragma unroll
  for (int q = 0; q < 2; ++q)
#pragma unroll
    for (int nf = 0; nf < 4; ++nf) acc[q][nf] = (f32x4){0.f, 0.f, 0.f, 0.f};

  const int x = bx + l15;

  f16x8 wbd[2][4];
#pragma unroll
  for (int nf = 0; nf < 4; ++nf)
    wbd[0][nf] = *(const f16x8*)(wdp + (lg * 64 + nf * 16 + l15) * 8);

  for (int kk = 0; kk < 9; ++kk) {
    const int kdy = kk / 3 - 1, kdx = kk - (kk / 3) * 3 - 1;
    f16x8 af[2][2];
#pragma unroll
    for (int q = 0; q < 2; ++q) {
      const int y = by + w * 2 + q;
      const int px_lin = (w * 2 + q) * 16 + l15;
      const float2 o2 = *(const float2*)(&offsL[px_lin * OSTR + kk * 2]);
      float ys = (float)(y + kdy) + o2.x;
      float xs = (float)(x + kdx) + o2.y;
      float y0f = floorf(ys), x0f = floorf(xs);
      float wy = ys - y0f, wx = xs - x0f;
      int y0 = (int)y0f, x0i = (int)x0f;
      int y1 = y0 + 1, x1 = x0i + 1;
      float vy0 = (y0 >= 0 && y0 < HW) ? 1.f : 0.f;
      float vy1 = (y1 >= 0 && y1 < HW) ? 1.f : 0.f;
      float vx0 = (x0i >= 0 && x0i < HW) ? 1.f : 0.f;
      float vx1 = (x1 >= 0 && x1 < HW) ? 1.f : 0.f;
      int y0c = min(max(y0, 0), HW - 1), y1c = min(max(y1, 0), HW - 1);
      int x0c = min(max(x0i, 0), HW - 1), x1c = min(max(x1, 0), HW - 1);
      __half2 h00 = __float2half2_rn((1.f - wy) * (1.f - wx) * vy0 * vx0);
      __half2 h01 = __float2half2_rn((1.f - wy) * wx * vy0 * vx1);
      __half2 h10 = __float2half2_rn(wy * (1.f - wx) * vy1 * vx0);
      __half2 h11 = __float2half2_rn(wy * wx * vy1 * vx1);

      const int wy0 = y0c - by + 2, wy1 = y1c - by + 2;
      const int wx0 = x0c - bx + 2, wx1 = x1c - bx + 2;
      const bool inw = ((unsigned)wy0 < 20u) && ((unsigned)wy1 < 20u) &&
                       ((unsigned)wx0 < 20u) && ((unsigned)wx1 < 20u);
      const int r00 = wy0 * 20 + wx0, r01 = wy0 * 20 + wx1;
      const int r10 = wy1 * 20 + wx0, r11 = wy1 * 20 + wx1;
      const unsigned short* p00 = tb + (y0c * HW + x0c) * 64 + lg * 8;
      const unsigned short* p01 = tb + (y0c * HW + x1c) * 64 + lg * 8;
      const unsigned short* p10 = tb + (y1c * HW + x0c) * 64 + lg * 8;
      const unsigned short* p11 = tb + (y1c * HW + x1c) * 64 + lg * 8;
#pragma unroll
      for (int ks = 0; ks < 2; ++ks) {
        uint4 c0, c1, c2, c3;
        const int ko = ks * 32 + lg * 8;
        if (inw) {
          c0 = *(const uint4*)(bufW + r00 * WSTR + ko);
          c1 = *(const uint4*)(bufW + r01 * WSTR + ko);
          c2 = *(const uint4*)(bufW + r10 * WSTR + ko);
          c3 = *(const uint4*)(bufW + r11 * WSTR + ko);
        } else {
          c0 = *(const uint4*)(p00 + ks * 32);
          c1 = *(const uint4*)(p01 + ks * 32);
          c2 = *(const uint4*)(p10 + ks * 32);
          c3 = *(const uint4*)(p11 + ks * 32);
        }
        uint4 r = blend4(c0, c1, c2, c3, h00, h01, h10, h11);
        af[q][ks] = *(const f16x8*)&r;
      }
    }

#pragma unroll
    for (int ks = 0; ks < 2; ++ks) {
      const int jt = kk * 2 + ks;
      if (jt < 17) {
        const int kb = (jt + 1) * 4 + lg;
#pragma unroll
        for (int nf = 0; nf < 4; ++nf)
          wbd[ks ^ 1][nf] = *(const f16x8*)(wdp + (kb * 64 + nf * 16 + l15) * 8);
      }
#pragma unroll
      for (int q = 0; q < 2; ++q)
#pragma unroll
        for (int nf = 0; nf < 4; ++nf)
          acc[q][nf] = __builtin_amdgcn_mfma_f32_16x16x32_f16(af[q][ks], wbd[ks][nf], acc[q][nf], 0, 0, 0);
    }
  }

  const int px0 = bx + lg * 4;
#pragma unroll
  for (int q = 0; q < 2; ++q) {
    const int py = by + w * 2 + q;
#pragma unroll
    for (int nf = 0; nf < 4; ++nf) {
      const int oc = nf * 16 + l15;
      float4 o;
      o.x = acc[q][nf][0];
      o.y = acc[q][nf][1];
      o.z = acc[q][nf][2];
      o.w = acc[q][nf][3];
      *(float4*)(out + (size_t)(b * 64 + oc) * PLANE + py * HW + px0) = o;
    }
  }
}

extern "C" void kernel_launch(void* const* d_in, const int* in_sizes, int n_in,
                              void* d_out, int out_size, void* d_ws, size_t ws_size,
                              hipStream_t stream) {
  const float* ref = (const float*)d_in[0];
  const float* tgt = (const float*)d_in[1];
  const float* w1  = (const float*)d_in[2];
  const float* b1  = (const float*)d_in[3];
  const float* w2  = (const float*)d_in[4];
  const float* b2  = (const float*)d_in[5];
  const float* wd  = (const float*)d_in[6];
  float* out = (float*)d_out;

  char* ws = (char*)d_ws;
  unsigned short* xref = (unsigned short*)ws;                   // 16777216 B
  unsigned short* xtgt = (unsigned short*)(ws + 16777216);      // 16777216 B
  unsigned short* w1p  = (unsigned short*)(ws + 33554432);      // 147456 B
  unsigned short* w2p  = (unsigned short*)(ws + 33701888);      // 36864 B
  unsigned short* wdp  = (unsigned short*)(ws + 33738752);      // 73728 B; end = 33812480

  pack_all_kernel<<<504, 256, 0, stream>>>(w1, w2, wd, w1p, w2p, wdp);

  to_nhwc_kernel<<<dim3(4, 128, 8), 256, 0, stream>>>(ref, tgt, xref, xtgt);

  mega_kernel<<<512, 512, 0, stream>>>(xref, xtgt, w1p, b1, w2p, b2, wdp, out);
}

// Round 15
// 108.196 us; speedup vs baseline: 1.2085x; 1.1756x over previous
//
#include <hip/hip_runtime.h>
#include <hip/hip_fp16.h>

#define HW 128
#define PLANE (HW * HW)
#define OSTR 22   // floats per offsL pixel row

typedef __attribute__((ext_vector_type(8))) _Float16 f16x8;
typedef __attribute__((ext_vector_type(4))) float f32x4;

__device__ __forceinline__ unsigned short f2h(float f) {
  return __half_as_ushort(__float2half(f));
}

// XCD-aware bijective swizzle (nwg % 8 == 0): XCD k gets a contiguous chunk.
__device__ __forceinline__ void tile_from_bid_512(int bid, int& b, int& by, int& bx) {
  int wg = (bid & 7) * 64 + (bid >> 3);
  b = wg >> 6;
  int t = wg & 63;
  by = (t >> 3) << 4;
  bx = (t & 7) << 4;
}

// ---------------- fused weight packing (all three) ----------------
__global__ __launch_bounds__(256) void pack_all_kernel(
    const float* __restrict__ w1, const float* __restrict__ w2,
    const float* __restrict__ wd, unsigned short* __restrict__ w1p,
    unsigned short* __restrict__ w2p, unsigned short* __restrict__ wdp) {
  int idx = blockIdx.x * 256 + threadIdx.x;
  if (idx < 73728) {
    int k = idx >> 6, n = idx & 63;
    int tap = k >> 7, ic = k & 127;
    w1p[((k >> 3) * 64 + n) * 8 + (k & 7)] = f2h(w1[(n * 128 + ic) * 9 + tap]);
  } else if (idx < 73728 + 18432) {
    int i = idx - 73728;
    int k = i >> 5, n = i & 31;
    int tap = k >> 6, ic = k & 63;
    float v = (n < 18) ? w2[(n * 64 + ic) * 9 + tap] : 0.f;
    w2p[((k >> 3) * 32 + n) * 8 + (k & 7)] = f2h(v);
  } else if (idx < 73728 + 18432 + 36864) {
    int i = idx - 73728 - 18432;
    int k = i >> 6, n = i & 63;
    int tap = k >> 6, ic = k & 63;
    wdp[((k >> 3) * 64 + n) * 8 + (k & 7)] = f2h(wd[(n * 64 + ic) * 9 + tap]);
  }
}

// ---------------- ref,tgt NCHW fp32 -> NHWC fp16 ----------------
__global__ __launch_bounds__(256) void to_nhwc_kernel(
    const float* __restrict__ ref, const float* __restrict__ tgt,
    unsigned short* __restrict__ xref, unsigned short* __restrict__ xtgt) {
  __shared__ unsigned short lds[32][136];
  const int b = blockIdx.z, y = blockIdx.y, x0 = blockIdx.x * 32;
  for (int idx = threadIdx.x; idx < 4096; idx += 256) {
    int ic = idx >> 5, px = idx & 31;
    const float* src = (ic < 64) ? ref : tgt;
    lds[px][ic] = f2h(src[(b * 64 + (ic & 63)) * PLANE + y * HW + x0 + px]);
  }
  __syncthreads();
  for (int idx = threadIdx.x; idx < 512; idx += 256) {
    int px = idx >> 4, g = idx & 15;
    uint4 v = *(const uint4*)&lds[px][g * 8];
    size_t base = ((size_t)(b * HW + y) * HW + x0 + px) * 64;
    if (g < 8)
      *(uint4*)(xref + base + g * 8) = v;
    else
      *(uint4*)(xtgt + base + (g - 8) * 8) = v;
  }
}

__device__ __forceinline__ uint4 blend4(uint4 a, uint4 b, uint4 c, uint4 d,
                                        __half2 h00, __half2 h01, __half2 h10, __half2 h11) {
  union U { uint4 u; __half2 h[4]; };
  U A, B, C, D, R;
  A.u = a; B.u = b; C.u = c; D.u = d;
#pragma unroll
  for (int i = 0; i < 4; ++i)
    R.h[i] = __hfma2(D.h[i], h11, __hfma2(C.h[i], h10, __hfma2(B.h[i], h01, __hmul2(A.h[i], h00))));
  return R.u;
}

// ---------------- megakernel v7: XOR-swizzled window + relaxed VGPR bound, NO manual dbuf ----------------
// = round-12 v4 (v2 structure, stride-64 XOR window, plain inline weight loads)
// with __launch_bounds__(512, 2) so the XOR addressing doesn't spill (v4's only
// failure mode: VGPR pinned at 64 -> 160B/thread scratch). LDS 73728 B -> 2 blocks/CU.
__global__ __launch_bounds__(512, 2) void mega_kernel(
    const unsigned short* __restrict__ xref, const unsigned short* __restrict__ xtgt,
    const unsigned short* __restrict__ w1p, const float* __restrict__ b1,
    const unsigned short* __restrict__ w2p, const float* __restrict__ b2,
    const unsigned short* __restrict__ wdp, float* __restrict__ out) {
  __shared__ __align__(16) unsigned short bufW[400 * 64];  // 51200 B
  __shared__ __align__(8) float offsL[256 * OSTR];         // 22528 B; total 73728 B

  int b, by, bx;
  tile_from_bid_512(blockIdx.x, b, by, bx);
  const int tid = threadIdx.x, lane = tid & 63, w = tid >> 6;
  const int l15 = lane & 15, lg = lane >> 4;

  const unsigned short* rb = xref + (size_t)b * PLANE * 64;
  const unsigned short* tb = xtgt + (size_t)b * PLANE * 64;

  auto STAGE = [&](const unsigned short* src) {
    for (int i = tid; i < 3200; i += 512) {
      int rec = i >> 3, g = i & 7;
      int wy = rec / 20, wx = rec - wy * 20;
      int gy = by - 2 + wy, gx = bx - 2 + wx;
      uint4 v = make_uint4(0u, 0u, 0u, 0u);
      if ((unsigned)gy < 128u && (unsigned)gx < 128u)
        v = *(const uint4*)(src + ((size_t)gy * HW + gx) * 64 + g * 8);
      *(uint4*)(bufW + rec * 64 + ((g * 8) ^ ((rec & 7) << 3))) = v;
    }
  };

  int pyv[3], pxv[3];
#pragma unroll
  for (int n = 0; n < 3; ++n) {
    int p = (w * 3 + n) * 16 + l15;
    p = min(p, 323);
    pyv[n] = p / 18;
    pxv[n] = p - pyv[n] * 18;
  }

  f32x4 acc1[4][3];
#pragma unroll
  for (int mf = 0; mf < 4; ++mf)
#pragma unroll
    for (int n = 0; n < 3; ++n) acc1[mf][n] = (f32x4){0.f, 0.f, 0.f, 0.f};

  // one K-half (c=0 ref, c=1 tgt) of conv1 over whatever is staged in bufW
  auto CONV1_HALF = [&](int c) {
#pragma unroll
    for (int tap = 0; tap < 9; ++tap) {
      const int ty = tap / 3, tx = tap - ty * 3;
#pragma unroll
      for (int ks = 0; ks < 2; ++ks) {
        f16x8 bp[3];
#pragma unroll
        for (int n = 0; n < 3; ++n) {
          int rec = (pyv[n] + ty) * 20 + pxv[n] + tx;
          bp[n] = *(const f16x8*)(bufW + rec * 64 + ((ks * 32 + lg * 8) ^ ((rec & 7) << 3)));
        }
        const int kb = tap * 16 + c * 8 + ks * 4 + lg;
        f16x8 aw[4];
#pragma unroll
        for (int mf = 0; mf < 4; ++mf)
          aw[mf] = *(const f16x8*)(w1p + (kb * 64 + mf * 16 + l15) * 8);
#pragma unroll
        for (int mf = 0; mf < 4; ++mf)
#pragma unroll
          for (int n = 0; n < 3; ++n)
            acc1[mf][n] = __builtin_amdgcn_mfma_f32_16x16x32_f16(aw[mf], bp[n], acc1[mf][n], 0, 0, 0);
      }
    }
  };

  STAGE(tb);            // s1: tgt window
  __syncthreads();
  CONV1_HALF(1);        // s2: tgt half of K
  __syncthreads();
  STAGE(rb);            // s3: ref window (overwrite)
  __syncthreads();
  CONV1_HALF(0);        // s4: ref half of K
  __syncthreads();

  // s5: hmid -> bufW overlay (18x18, swizzled), MASKED to 0 outside image
  unsigned short* hmidL = bufW;
#pragma unroll
  for (int mf = 0; mf < 4; ++mf) {
    const float4 bv = ((const float4*)b1)[mf * 4 + lg];
#pragma unroll
    for (int n = 0; n < 3; ++n) {
      const int p = (w * 3 + n) * 16 + l15;
      const bool valid = ((unsigned)(by - 1 + pyv[n]) < 128u) &&
                         ((unsigned)(bx - 1 + pxv[n]) < 128u);
      const float m = valid ? 1.f : 0.f;
      float v0 = acc1[mf][n][0] + bv.x;
      float v1 = acc1[mf][n][1] + bv.y;
      float v2 = acc1[mf][n][2] + bv.z;
      float v3 = acc1[mf][n][3] + bv.w;
      v0 = ((v0 >= 0.f) ? v0 : 0.1f * v0) * m;
      v1 = ((v1 >= 0.f) ? v1 : 0.1f * v1) * m;
      v2 = ((v2 >= 0.f) ? v2 : 0.1f * v2) * m;
      v3 = ((v3 >= 0.f) ? v3 : 0.1f * v3) * m;
      ushort4 s;
      s.x = f2h(v0); s.y = f2h(v1); s.z = f2h(v2); s.w = f2h(v3);
      *(ushort4*)(hmidL + p * 64 + ((mf * 16 + lg * 4) ^ ((p & 7) << 3))) = s;
    }
  }
  __syncthreads();

  // s6: conv2 (in LDS): A=hmid pixels, B=w2p (N=32, 18 valid) -> offsL
  f32x4 acc2[2][2];
#pragma unroll
  for (int q = 0; q < 2; ++q)
#pragma unroll
    for (int nf = 0; nf < 2; ++nf) acc2[q][nf] = (f32x4){0.f, 0.f, 0.f, 0.f};

#pragma unroll
  for (int tap = 0; tap < 9; ++tap) {
    const int ty = tap / 3, tx = tap - ty * 3;
#pragma unroll
    for (int ks = 0; ks < 2; ++ks) {
      f16x8 ap[2];
#pragma unroll
      for (int q = 0; q < 2; ++q) {
        int p = (w * 2 + q + ty) * 18 + l15 + tx;
        ap[q] = *(const f16x8*)(hmidL + p * 64 + ((ks * 32 + lg * 8) ^ ((p & 7) << 3)));
      }
      const int kb = tap * 8 + ks * 4 + lg;
      f16x8 bw[2];
#pragma unroll
      for (int nf = 0; nf < 2; ++nf)
        bw[nf] = *(const f16x8*)(w2p + (kb * 32 + nf * 16 + l15) * 8);
#pragma unroll
      for (int q = 0; q < 2; ++q)
#pragma unroll
        for (int nf = 0; nf < 2; ++nf)
          acc2[q][nf] = __builtin_amdgcn_mfma_f32_16x16x32_f16(ap[q], bw[nf], acc2[q][nf], 0, 0, 0);
    }
  }
#pragma unroll
  for (int nf = 0; nf < 2; ++nf) {
    const int oc = nf * 16 + l15;
    if (oc < 18) {
      const float bias = b2[oc];
#pragma unroll
      for (int q = 0; q < 2; ++q)
#pragma unroll
        for (int reg = 0; reg < 4; ++reg) {
          int px = (w * 2 + q) * 16 + lg * 4 + reg;
          offsL[px * OSTR + oc] = acc2[q][nf][reg] + bias;
        }
    }
  }
  __syncthreads();

  STAGE(tb);            // s7: re-stage tgt window
  __syncthreads();

  // s8: deform: gather from bufW + fp16 MFMA. A=sampled px, B=wd
  f32x4 acc[2][4];
#pragma unroll
  for (int q = 0; q < 2; ++q)
#pragma unroll
    for (int nf = 0; nf < 4; ++nf) acc[q][nf] = (f32x4){0.f, 0.f, 0.f, 0.f};

  const int x = bx + l15;

  for (int kk = 0; kk < 9; ++kk) {
    const int kdy = kk / 3 - 1, kdx = kk - (kk / 3) * 3 - 1;
    f16x8 af[2][2];
#pragma unroll
    for (int q = 0; q < 2; ++q) {
      const int y = by + w * 2 + q;
      const int px_lin = (w * 2 + q) * 16 + l15;
      const float2 o2 = *(const float2*)(&offsL[px_lin * OSTR + kk * 2]);
      float ys = (float)(y + kdy) + o2.x;
      float xs = (float)(x + kdx) + o2.y;
      float y0f = floorf(ys), x0f = floorf(xs);
      float wy = ys - y0f, wx = xs - x0f;
      int y0 = (int)y0f, x0i = (int)x0f;
      int y1 = y0 + 1, x1 = x0i + 1;
      float vy0 = (y0 >= 0 && y0 < HW) ? 1.f : 0.f;
      float vy1 = (y1 >= 0 && y1 < HW) ? 1.f : 0.f;
      float vx0 = (x0i >= 0 && x0i < HW) ? 1.f : 0.f;
      float vx1 = (x1 >= 0 && x1 < HW) ? 1.f : 0.f;
      int y0c = min(max(y0, 0), HW - 1), y1c = min(max(y1, 0), HW - 1);
      int x0c = min(max(x0i, 0), HW - 1), x1c = min(max(x1, 0), HW - 1);
      __half2 h00 = __float2half2_rn((1.f - wy) * (1.f - wx) * vy0 * vx0);
      __half2 h01 = __float2half2_rn((1.f - wy) * wx * vy0 * vx1);
      __half2 h10 = __float2half2_rn(wy * (1.f - wx) * vy1 * vx0);
      __half2 h11 = __float2half2_rn(wy * wx * vy1 * vx1);

      const int wy0 = y0c - by + 2, wy1 = y1c - by + 2;
      const int wx0 = x0c - bx + 2, wx1 = x1c - bx + 2;
      const bool inw = ((unsigned)wy0 < 20u) && ((unsigned)wy1 < 20u) &&
                       ((unsigned)wx0 < 20u) && ((unsigned)wx1 < 20u);
      const int r00 = wy0 * 20 + wx0, r01 = wy0 * 20 + wx1;
      const int r10 = wy1 * 20 + wx0, r11 = wy1 * 20 + wx1;
      const unsigned short* p00 = tb + (y0c * HW + x0c) * 64 + lg * 8;
      const unsigned short* p01 = tb + (y0c * HW + x1c) * 64 + lg * 8;
      const unsigned short* p10 = tb + (y1c * HW + x0c) * 64 + lg * 8;
      const unsigned short* p11 = tb + (y1c * HW + x1c) * 64 + lg * 8;
#pragma unroll
      for (int ks = 0; ks < 2; ++ks) {
        uint4 c0, c1, c2, c3;
        const int ko = ks * 32 + lg * 8;
        if (inw) {
          c0 = *(const uint4*)(bufW + r00 * 64 + (ko ^ ((r00 & 7) << 3)));
          c1 = *(const uint4*)(bufW + r01 * 64 + (ko ^ ((r01 & 7) << 3)));
          c2 = *(const uint4*)(bufW + r10 * 64 + (ko ^ ((r10 & 7) << 3)));
          c3 = *(const uint4*)(bufW + r11 * 64 + (ko ^ ((r11 & 7) << 3)));
        } else {
          c0 = *(const uint4*)(p00 + ks * 32);
          c1 = *(const uint4*)(p01 + ks * 32);
          c2 = *(const uint4*)(p10 + ks * 32);
          c3 = *(const uint4*)(p11 + ks * 32);
        }
        uint4 r = blend4(c0, c1, c2, c3, h00, h01, h10, h11);
        af[q][ks] = *(const f16x8*)&r;
      }
    }

#pragma unroll
    for (int ks = 0; ks < 2; ++ks) {
      const int kb = kk * 8 + ks * 4 + lg;
      f16x8 bw[4];
#pragma unroll
      for (int nf = 0; nf < 4; ++nf)
        bw[nf] = *(const f16x8*)(wdp + (kb * 64 + nf * 16 + l15) * 8);
#pragma unroll
      for (int q = 0; q < 2; ++q)
#pragma unroll
        for (int nf = 0; nf < 4; ++nf)
          acc[q][nf] = __builtin_amdgcn_mfma_f32_16x16x32_f16(af[q][ks], bw[nf], acc[q][nf], 0, 0, 0);
    }
  }

  const int px0 = bx + lg * 4;
#pragma unroll
  for (int q = 0; q < 2; ++q) {
    const int py = by + w * 2 + q;
#pragma unroll
    for (int nf = 0; nf < 4; ++nf) {
      const int oc = nf * 16 + l15;
      float4 o;
      o.x = acc[q][nf][0];
      o.y = acc[q][nf][1];
      o.z = acc[q][nf][2];
      o.w = acc[q][nf][3];
      *(float4*)(out + (size_t)(b * 64 + oc) * PLANE + py * HW + px0) = o;
    }
  }
}

extern "C" void kernel_launch(void* const* d_in, const int* in_sizes, int n_in,
                              void* d_out, int out_size, void* d_ws, size_t ws_size,
                              hipStream_t stream) {
  const float* ref = (const float*)d_in[0];
  const float* tgt = (const float*)d_in[1];
  const float* w1  = (const float*)d_in[2];
  const float* b1  = (const float*)d_in[3];
  const float* w2  = (const float*)d_in[4];
  const float* b2  = (const float*)d_in[5];
  const float* wd  = (const float*)d_in[6];
  float* out = (float*)d_out;

  char* ws = (char*)d_ws;
  unsigned short* xref = (unsigned short*)ws;                   // 16777216 B
  unsigned short* xtgt = (unsigned short*)(ws + 16777216);      // 16777216 B
  unsigned short* w1p  = (unsigned short*)(ws + 33554432);      // 147456 B
  unsigned short* w2p  = (unsigned short*)(ws + 33701888);      // 36864 B
  unsigned short* wdp  = (unsigned short*)(ws + 33738752);      // 73728 B; end = 33812480

  pack_all_kernel<<<504, 256, 0, stream>>>(w1, w2, wd, w1p, w2p, wdp);

  to_nhwc_kernel<<<dim3(4, 128, 8), 256, 0, stream>>>(ref, tgt, xref, xtgt);

  mega_kernel<<<512, 512, 0, stream>>>(xref, xtgt, w1p, b1, w2p, b2, wdp, out);
}